// Round 5
// baseline (1630.426 us; speedup 1.0000x reference)
//
#include <hip/hip_runtime.h>

// Ocean advection + 3x3 binomial smoothing, 48 steps, fp32.
// Register-streaming kernel (validated in R4) + explicit 1-iteration software
// pipeline: T row q+3 and u/g/m row q+2 prefetched into registers while
// computing advect(q+1)/smooth(q). Batch-co-XCD block swizzle for mask L2 reuse.
// No LDS, no __syncthreads.

#define DEG2RAD 0.017453292519943295f
#define R_EARTH 6371000.0f
#define DT_S 600.0f

constexpr int NT    = 256;   // 4 waves / block
constexpr int STRIP = 8;     // output rows per wave
constexpr int WPW   = 256;   // cols per wave (64 lanes x float4)

struct Row { float4 t; float2 hl, hr; };   // T row + left/right 2-col halos
struct Fld { float4 u, g, m; };            // ug/vg/mask row (wave's 4 cols/lane)

__global__ __launch_bounds__(256)
void prep_kernel(const float* __restrict__ lat, const float* __restrict__ lon,
                 float* __restrict__ coef, int H) {
    int h = blockIdx.x * blockDim.x + threadIdx.x;
    if (h < H) {
        float dlon = lon[1] - lon[0];
        coef[h] = 1.0f / (R_EARTH * DEG2RAD * dlon * cosf(lat[h] * DEG2RAD));
    }
    if (h == 0) {
        float dlat = lat[1] - lat[0];
        coef[H] = 1.0f / (R_EARTH * DEG2RAD * dlat);
    }
}

__global__ __launch_bounds__(256, 4)
void stream_kernel(const float* __restrict__ Tin, const float* __restrict__ ug,
                   const float* __restrict__ vg, const float* __restrict__ mask,
                   const float* __restrict__ coef, float* __restrict__ Tout,
                   int H, int W, int nbx, int nxy, int swz) {
    const int lane = threadIdx.x & 63;
    const int wv   = threadIdx.x >> 6;
    int id = blockIdx.x;
    int xy, b;
    if (swz) {  // ids of same-(x,y) blocks across the 8 batches differ by 8 -> same XCD
        xy = (id >> 6) * 8 + (id & 7);
        b  = (id >> 3) & 7;
    } else {
        xy = id % nxy;
        b  = id / nxy;
    }
    const int ws = (xy % nbx) * WPW;
    const int hs = ((xy / nbx) * 4 + wv) * STRIP;
    if (hs >= H) return;

    const size_t plane = (size_t)H * W;
    const float* __restrict__ Tb  = Tin + b * plane;
    const float* __restrict__ ugb = ug  + b * plane;
    const float* __restrict__ vgb = vg  + b * plane;
    float* __restrict__ To = Tout + b * plane;
    const float inv_dy = coef[H];
    const bool atL = (ws == 0);
    const bool atR = (ws + WPW >= W);
    const bool isL = (lane == 0);
    const bool isR = (lane == 63);
    const int gw = ws + 4 * lane;

    auto clampr = [&](int r) { return min(max(r, 0), H - 1); };
    auto loadT = [&](int r) -> Row {
        Row R; size_t ro = (size_t)clampr(r) * W;
        R.t = *(const float4*)(Tb + ro + gw);
        if (!atL) { float4 q = *(const float4*)(Tb + ro + (ws - 4)); R.hl = make_float2(q.z, q.w); }
        else R.hl = make_float2(0.f, 0.f);
        if (!atR) { float4 q = *(const float4*)(Tb + ro + (ws + WPW)); R.hr = make_float2(q.x, q.y); }
        else R.hr = make_float2(0.f, 0.f);
        return R;
    };
    auto loadF = [&](int r) -> Fld {
        Fld F; size_t ro = (size_t)clampr(r) * W;   // clamped addr; OOB rows unused
        F.u = *(const float4*)(ugb + ro + gw);
        F.g = *(const float4*)(vgb + ro + gw);
        F.m = *(const float4*)(mask + ro + gw);
        return F;
    };

    // advect row r using T rows r-1,r,r+1 (Rm,Rc,Rp) and fields F(r); zeros if OOB.
    auto advect = [&](int r, const Row& Rm, const Row& Rc, const Row& Rp, const Fld& F,
                      float4& a, float& aL, float& aR) {
        if (r < 0 || r >= H) {
            a = make_float4(0.f, 0.f, 0.f, 0.f); aL = 0.f; aR = 0.f; return;
        }
        const size_t ro = (size_t)r * W;
        // broadcast halo field loads (issued early; single cache line each)
        float uL = 0.f, gL = 0.f, mL = 0.f, uR = 0.f, gR = 0.f, mR = 0.f;
        if (!atL) {
            uL = ((const float4*)(ugb + ro + (ws - 4)))->w;
            gL = ((const float4*)(vgb + ro + (ws - 4)))->w;
            mL = ((const float4*)(mask + ro + (ws - 4)))->w;
        }
        if (!atR) {
            uR = ((const float4*)(ugb + ro + (ws + WPW)))->x;
            gR = ((const float4*)(vgb + ro + (ws + WPW)))->x;
            mR = ((const float4*)(mask + ro + (ws + WPW)))->x;
        }
        const float ix  = coef[r];
        const float sy  = (r == 0 || r == H - 1) ? inv_dy : 0.5f * inv_dy;
        const float sxh = 0.5f * ix;
        float cLw = __shfl_up(Rc.t.w, 1);
        float cRx = __shfl_down(Rc.t.x, 1);
        float sxx = sxh, sxw = sxh;
        if (isL) { if (atL) { cLw = Rc.t.x; sxx = ix; } else cLw = Rc.hl.y; }
        if (isR) { if (atR) { cRx = Rc.t.w; sxw = ix; } else cRx = Rc.hr.x; }
        a.x = Rc.t.x + DT_S * (-(F.u.x * ((Rc.t.y - cLw) * sxx) + F.g.x * ((Rp.t.x - Rm.t.x) * sy)) * F.m.x);
        a.y = Rc.t.y + DT_S * (-(F.u.y * ((Rc.t.z - Rc.t.x) * sxh) + F.g.y * ((Rp.t.y - Rm.t.y) * sy)) * F.m.y);
        a.z = Rc.t.z + DT_S * (-(F.u.z * ((Rc.t.w - Rc.t.y) * sxh) + F.g.z * ((Rp.t.z - Rm.t.z) * sy)) * F.m.z);
        a.w = Rc.t.w + DT_S * (-(F.u.w * ((cRx - Rc.t.z) * sxw) + F.g.w * ((Rp.t.w - Rm.t.w) * sy)) * F.m.w);
        // halo advected cols (valid on lane0/lane63 only; used only there)
        aL = (!atL) ? (Rc.hl.y + DT_S * (-(uL * ((Rc.t.x - Rc.hl.x) * sxh)
                                        + gL * ((Rp.hl.y - Rm.hl.y) * sy)) * mL)) : 0.f;
        aR = (!atR) ? (Rc.hr.x + DT_S * (-(uR * ((Rc.hr.y - Rc.t.w) * sxh)
                                        + gR * ((Rp.hr.x - Rm.hr.x) * sy)) * mR)) : 0.f;
    };

    // ---- warm-up: issue ~5 T rows + 3 field rows of loads up front ----
    Row Rm2 = loadT(hs - 2), Rm1 = loadT(hs - 1);
    Row Ra = loadT(hs), Rb = loadT(hs + 1), Rc = loadT(hs + 2);
    Fld Fm1 = loadF(hs - 1), F0 = loadF(hs), Fb = loadF(hs + 1);

    float4 ap, ac, an;
    float aLp, aRp, aLc, aRc, aLn, aRn;
    advect(hs - 1, Rm2, Rm1, Ra, Fm1, ap, aLp, aRp);
    advect(hs,     Rm1, Ra,  Rb, F0,  ac, aLc, aRc);
    float4 mQ = F0.m;

    #pragma unroll
    for (int i = 0; i < STRIP; ++i) {
        const int q = hs + i;
        // prefetch one iteration ahead (consumed next iteration)
        Row Rd = loadT(q + 3);
        Fld Fn = loadF(q + 2);
        // compute with data loaded last iteration
        advect(q + 1, Ra, Rb, Rc, Fb, an, aLn, aRn);
        // separable 1-2-1 smooth + store row q
        float4 v;
        v.x = ap.x + 2.f * ac.x + an.x;
        v.y = ap.y + 2.f * ac.y + an.y;
        v.z = ap.z + 2.f * ac.z + an.z;
        v.w = ap.w + 2.f * ac.w + an.w;
        float vL  = aLp + 2.f * aLc + aLn;
        float vR  = aRp + 2.f * aRc + aRn;
        float vLw = __shfl_up(v.w, 1);
        float vRx = __shfl_down(v.x, 1);
        if (isL) vLw = atL ? 0.f : vL;
        if (isR) vRx = atR ? 0.f : vR;
        float4 o;
        o.x = (vLw + 2.f * v.x + v.y) * 0.0625f * mQ.x;
        o.y = (v.x + 2.f * v.y + v.z) * 0.0625f * mQ.y;
        o.z = (v.y + 2.f * v.z + v.w) * 0.0625f * mQ.z;
        o.w = (v.z + 2.f * v.w + vRx) * 0.0625f * mQ.w;
        if (q < H) *(float4*)(To + (size_t)q * W + gw) = o;
        // shift pipelines
        Ra = Rb; Rb = Rc; Rc = Rd;
        mQ = Fb.m; Fb = Fn;
        ap = ac; ac = an;
        aLp = aLc; aLc = aLn; aRp = aRc; aRc = aRn;
    }
}

// ---------- generic fallback (round-1 LDS tile kernel, validated) ----------
constexpr int FTW = 64, FTH = 32;
constexpr int FSTW = FTW + 4, FSTH = FTH + 4;
constexpr int FMTW = FTW + 2, FMTH = FTH + 2;

__global__ __launch_bounds__(256)
void step_tile(const float* __restrict__ Tin, const float* __restrict__ ug,
               const float* __restrict__ vg, const float* __restrict__ mask,
               const float* __restrict__ coef, float* __restrict__ Tout,
               int H, int W) {
    __shared__ float sT[FSTH][FSTW];
    __shared__ float sM[FMTH][FMTW];
    const int tid = threadIdx.x;
    const int w0 = blockIdx.x * FTW;
    const int h0 = blockIdx.y * FTH;
    const int b  = blockIdx.z;
    const long plane = (long)H * W;
    const float* Tb  = Tin + b * plane;
    const float* ugb = ug  + b * plane;
    const float* vgb = vg  + b * plane;
    const float inv_dy = coef[H];

    for (int i = tid; i < FSTH * FSTW; i += NT) {
        int r = i / FSTW, c = i - r * FSTW;
        int gh = min(max(h0 - 2 + r, 0), H - 1);
        int gw = min(max(w0 - 2 + c, 0), W - 1);
        sT[r][c] = Tb[gh * W + gw];
    }
    __syncthreads();
    for (int i = tid; i < FMTH * FMTW; i += NT) {
        int r = i / FMTW, c = i - r * FMTW;
        int gh = h0 - 1 + r, gw = w0 - 1 + c;
        float v = 0.0f;
        if (gh >= 0 && gh < H && gw >= 0 && gw < W) {
            int sr = r + 1, sc = c + 1;
            float ndy = sT[sr + 1][sc] - sT[sr - 1][sc];
            float ndx = sT[sr][sc + 1] - sT[sr][sc - 1];
            float sy  = (gh == 0 || gh == H - 1) ? inv_dy : 0.5f * inv_dy;
            float ix  = coef[gh];
            float sx  = (gw == 0 || gw == W - 1) ? ix : 0.5f * ix;
            int   gi  = gh * W + gw;
            float F   = -(ugb[gi] * (ndx * sx) + vgb[gi] * (ndy * sy)) * mask[gi];
            v = sT[sr][sc] + DT_S * F;
        }
        sM[r][c] = v;
    }
    __syncthreads();
    float* To = Tout + b * plane;
    for (int i = tid; i < FTH * FTW; i += NT) {
        int r = i >> 6, c = i & (FTW - 1);
        int gh = h0 + r, gw = w0 + c;
        if (gh < H && gw < W) {
            int sr = r + 1, sc = c + 1;
            float s = (sM[sr-1][sc-1] + sM[sr-1][sc+1] + sM[sr+1][sc-1] + sM[sr+1][sc+1])
                    + 2.0f * (sM[sr-1][sc] + sM[sr+1][sc] + sM[sr][sc-1] + sM[sr][sc+1])
                    + 4.0f * sM[sr][sc];
            To[gh * W + gw] = s * 0.0625f * mask[gh * W + gw];
        }
    }
}

extern "C" void kernel_launch(void* const* d_in, const int* in_sizes, int n_in,
                              void* d_out, int out_size, void* d_ws, size_t ws_size,
                              hipStream_t stream) {
    const float* T0   = (const float*)d_in[0];
    const float* ug   = (const float*)d_in[1];
    const float* vg   = (const float*)d_in[2];
    const float* lat  = (const float*)d_in[3];
    const float* lon  = (const float*)d_in[4];
    const float* mask = (const float*)d_in[5];

    const int H = in_sizes[3];
    const int W = in_sizes[4];
    const int B = in_sizes[0] / (H * W);

    float* out  = (float*)d_out;
    float* ping = (float*)d_ws;                 // B*H*W floats
    float* coef = ping + (size_t)B * H * W;     // H+1 floats: 1/dx[h], then 1/dy

    prep_kernel<<<dim3((H + NT - 1) / NT), dim3(NT), 0, stream>>>(lat, lon, coef, H);

    const bool fast = (W % WPW) == 0;
    const int nbx = fast ? (W / WPW) : 1;
    const int nby = (H + 4 * STRIP - 1) / (4 * STRIP);
    const int nxy = nbx * nby;
    const int swz = (B == 8 && (nxy % 8) == 0) ? 1 : 0;

    dim3 gridS(nxy * B, 1, 1);
    dim3 gridF((W + FTW - 1) / FTW, (H + FTH - 1) / FTH, B);

    const int STEPS = 48;
    for (int i = 0; i < STEPS; ++i) {
        const float* src = (i == 0) ? T0 : ((i & 1) ? ping : out);
        float*       dst = (i & 1) ? out : ping;
        if (fast)
            stream_kernel<<<gridS, dim3(NT), 0, stream>>>(src, ug, vg, mask, coef, dst,
                                                          H, W, nbx, nxy, swz);
        else
            step_tile<<<gridF, dim3(NT), 0, stream>>>(src, ug, vg, mask, coef, dst, H, W);
    }
}